// Round 5
// baseline (455.580 us; speedup 1.0000x reference)
//
#include <hip/hip_runtime.h>
#include <hip/hip_bf16.h>

#define NB 64     // batch
#define NI 2048   // input capsules
#define ND 16     // d_in
#define NJ 32     // output capsules
#define NE 32     // d_out
#define NIP (NI/2)  // i-pairs
#define NKC 64    // split-K chunks in wsum

typedef __attribute__((ext_vector_type(8))) short bfrag;   // 8 bf16 (4 VGPRs)
typedef __attribute__((ext_vector_type(4))) float f32x4;

// float -> bf16 bits, round-to-nearest-even (scalar path, conv kernels)
__device__ inline short f2bf(float f) {
    unsigned u = __float_as_uint(f);
    unsigned r = u + 0x7fffu + ((u >> 16) & 1u);
    return (short)(r >> 16);
}

// two floats -> packed bf16x2 (v_cvt_pk_bf16_f32 on gfx950), RNE
__device__ inline unsigned pk2bf(float a, float b) {
    __hip_bfloat162 h = __float22bfloat162_rn(make_float2(a, b));
    return *reinterpret_cast<unsigned*>(&h);
}

// add value rotated by N within each 16-lane DPP row (row_ror:N)
template <int N>
__device__ inline float rot16_add(float v) {
    int r = __builtin_amdgcn_mov_dpp(__float_as_int(v), 0x120 + N, 0xf, 0xf, false);
    return v + __int_as_float(r);
}

// ---------------------------------------------------------------------------
// convw_k: W fp32 [NJ][NI][NE][ND] -> Wb bf16 [NJ][NIP][NE][32],
// Wb[j][ip][e][k] = W[j][ip*2 + (k>>4)][e][k&15]  (MFMA B-fragment layout).
// ---------------------------------------------------------------------------
__global__ __launch_bounds__(256) void convw_k(const float* __restrict__ W,
                                               short* __restrict__ Wb)
{
    const int t = blockIdx.x * 256 + threadIdx.x;   // 2^21 threads
    const int isel = t & 1;
    const int e    = (t >> 1) & 31;
    const int ip   = (t >> 6) & 1023;
    const int j    = t >> 16;

    const float4* src = reinterpret_cast<const float4*>(
        W + (((size_t)j * NI + ip * 2 + isel) * NE + e) * ND);
    float4 a = src[0], b = src[1], c = src[2], d = src[3];

    bfrag lo, hi;
    lo[0] = f2bf(a.x); lo[1] = f2bf(a.y); lo[2] = f2bf(a.z); lo[3] = f2bf(a.w);
    lo[4] = f2bf(b.x); lo[5] = f2bf(b.y); lo[6] = f2bf(b.z); lo[7] = f2bf(b.w);
    hi[0] = f2bf(c.x); hi[1] = f2bf(c.y); hi[2] = f2bf(c.z); hi[3] = f2bf(c.w);
    hi[4] = f2bf(d.x); hi[5] = f2bf(d.y); hi[6] = f2bf(d.z); hi[7] = f2bf(d.w);

    short* dst = Wb + ((((size_t)j * NIP + ip) * NE + e) * 32) + isel * 16;
    *reinterpret_cast<bfrag*>(dst)     = lo;
    *reinterpret_cast<bfrag*>(dst + 8) = hi;
}

// convx_k: x fp32 -> xb bf16, same [NB][NI][ND] layout. 8 elems/thread.
__global__ __launch_bounds__(256) void convx_k(const float* __restrict__ x,
                                               short* __restrict__ xb)
{
    const size_t t = (size_t)blockIdx.x * 256 + threadIdx.x;  // 262144 threads
    const float4* src = reinterpret_cast<const float4*>(x + t * 8);
    float4 a = src[0], b = src[1];
    bfrag v;
    v[0] = f2bf(a.x); v[1] = f2bf(a.y); v[2] = f2bf(a.z); v[3] = f2bf(a.w);
    v[4] = f2bf(b.x); v[5] = f2bf(b.y); v[6] = f2bf(b.z); v[7] = f2bf(b.w);
    *reinterpret_cast<bfrag*>(xb + t * 8) = v;
}

// ---------------------------------------------------------------------------
// logits_k: lgt[j][i][b] = sum_e Oacc[b,j,e] * u_hat[b,j,i,e]
// u_hat via mfma_16x16x32_bf16, K zero-padded (d=16). All operands bf16.
// grid (j=32, i-chunk=64 of 32), block 256 = 4 waves; wave = 16-b M-tile.
// ---------------------------------------------------------------------------
__global__ __launch_bounds__(256) void logits_k(
    const short* __restrict__ xb,     // [NB][NI][ND] bf16
    const short* __restrict__ Wb,     // [NJ][NIP][NE][32] bf16
    const float* __restrict__ Oacc,   // [NB][NJ][NE]
    float* __restrict__ lgt)          // [NJ][NI][NB]
{
    const int j    = blockIdx.x;
    const int i0   = blockIdx.y * 32;
    const int t    = threadIdx.x;
    const int wv   = t >> 6;
    const int ln   = t & 63;
    const int m    = ln & 15;
    const int quad = ln >> 4;

    // Hoist Oacc fragments: rows b = wv*16 + quad*4 + r, cols e = m / 16+m
    float O0[4], O1[4];
#pragma unroll
    for (int r = 0; r < 4; ++r) {
        int b = wv * 16 + quad * 4 + r;
        O0[r] = Oacc[((size_t)b * NJ + j) * NE + m];
        O1[r] = Oacc[((size_t)b * NJ + j) * NE + 16 + m];
    }

    const int  bA  = wv * 16 + m;   // A-operand row (b) this lane supplies
    const bool act = quad < 2;      // quads 0,1 carry k=0..15 (d); 2,3 zero pad
    const int  d0  = quad * 8;

#pragma unroll 2
    for (int il = 0; il < 32; ++il) {
        const int i = i0 + il;
        const int ip = i >> 1, isel = i & 1;
        bfrag av = (bfrag)0, bv0 = (bfrag)0, bv1 = (bfrag)0;
        if (act) {
            av = *reinterpret_cast<const bfrag*>(
                xb + ((size_t)bA * NI + i) * ND + d0);
            const short* wp = Wb + (((size_t)j * NIP + ip) * NE + m) * 32
                                 + isel * 16 + d0;
            bv0 = *reinterpret_cast<const bfrag*>(wp);
            bv1 = *reinterpret_cast<const bfrag*>(wp + 16 * 32);
        }
        f32x4 z = {0.f, 0.f, 0.f, 0.f};
        f32x4 U0 = __builtin_amdgcn_mfma_f32_16x16x32_bf16(av, bv0, z, 0, 0, 0);
        f32x4 U1 = __builtin_amdgcn_mfma_f32_16x16x32_bf16(av, bv1, z, 0, 0, 0);

        float lp[4];
#pragma unroll
        for (int r = 0; r < 4; ++r) {
            float v = fmaf(U0[r], O0[r], U1[r] * O1[r]);
            v = rot16_add<1>(v);
            v = rot16_add<2>(v);
            v = rot16_add<4>(v);
            v = rot16_add<8>(v);
            lp[r] = v;   // full sum over 32 e's, replicated across the 16-lane row
        }
        if (m == 0) {
            // b = wv*16 + quad*4 + r, r=0..3 -> contiguous float4
            float4 o = make_float4(lp[0], lp[1], lp[2], lp[3]);
            *reinterpret_cast<float4*>(
                lgt + ((size_t)j * NI + i) * NB + wv * 16 + quad * 4) = o;
        }
    }
}

// ---------------------------------------------------------------------------
// softmax_k: softmax over j on [j][i][b] layout, in place. One thread per
// (i,b) pair; consecutive threads -> consecutive b (coalesced).
// ---------------------------------------------------------------------------
__global__ __launch_bounds__(256) void softmax_k(float* __restrict__ lgt)
{
    const size_t tid = (size_t)blockIdx.x * 256 + threadIdx.x;  // (i,b)
    float* base = lgt + tid;      // lgt[j][tid], stride NI*NB between j's

    float v[NJ];
    float mx = -1e30f;
#pragma unroll
    for (int jj = 0; jj < NJ; ++jj) {
        v[jj] = base[(size_t)jj * NI * NB];
        mx = fmaxf(mx, v[jj]);
    }
    float sum = 0.f;
#pragma unroll
    for (int jj = 0; jj < NJ; ++jj) {
        v[jj] = __expf(v[jj] - mx);
        sum += v[jj];
    }
    const float inv = 1.0f / sum;
#pragma unroll
    for (int jj = 0; jj < NJ; ++jj) base[(size_t)jj * NI * NB] = v[jj] * inv;
}

// ---------------------------------------------------------------------------
// wsum_k: partial[kc][j][t*16+q] = per-block split-K partials of
// s[b,j,e] = sum_i c[j,i,b] * u_hat[b,j,i,e].
// A[b][k] = c*x (fp32 mul + packed bf16 cvt), B[e][k] = Wb (preconverted).
// K=32 chunk = 2 i's. NO atomics: 4 contiguous float4 stores per thread;
// reduce_k knows the (t,q)->(b,e) mapping.
// grid (j=32, kc=64), block 128 = 2 waves; wave = 2 M-tiles.
// ---------------------------------------------------------------------------
template <bool R0>
__global__ __launch_bounds__(128) void wsum_k(
    const float* __restrict__ x,      // [NB][NI][ND] fp32
    const short* __restrict__ Wb,     // [NJ][NIP][NE][32] bf16
    const float* __restrict__ c,      // [NJ][NI][NB], unused if R0
    float* __restrict__ partial)      // [NKC][NJ][128*16]
{
    const int j    = blockIdx.x;
    const int kc   = blockIdx.y;
    const int ip0  = kc * 16;          // 16 i-pairs = 32 i's
    const int t    = threadIdx.x;
    const int wv   = t >> 6;
    const int ln   = t & 63;
    const int m    = ln & 15;
    const int quad = ln >> 4;
    const int isel = quad >> 1;        // which of the 2 i's in the K-chunk
    const int d0   = (quad & 1) * 8;   // which 8 d's

    f32x4 acc[2][2];
#pragma unroll
    for (int a = 0; a < 2; ++a)
#pragma unroll
        for (int n = 0; n < 2; ++n) acc[a][n] = (f32x4){0.f, 0.f, 0.f, 0.f};

#pragma unroll 4
    for (int it = 0; it < 16; ++it) {
        const int ip = ip0 + it;
        const int ia = ip * 2 + isel;
        const short* wp = Wb + (((size_t)j * NIP + ip) * NE + m) * 32 + quad * 8;
        bfrag bv0 = *reinterpret_cast<const bfrag*>(wp);
        bfrag bv1 = *reinterpret_cast<const bfrag*>(wp + 16 * 32);
#pragma unroll
        for (int mt = 0; mt < 2; ++mt) {
            const int b = (wv * 2 + mt) * 16 + m;
            // coalesced: consecutive m-lanes -> consecutive b
            const float cc = R0 ? (1.0f / NJ)
                                : c[((size_t)j * NI + ia) * NB + b];
            const float4* xp = reinterpret_cast<const float4*>(
                x + ((size_t)b * NI + ia) * ND + d0);
            float4 x0 = xp[0], x1 = xp[1];
            bfrag av;
            unsigned* avu = reinterpret_cast<unsigned*>(&av);
            avu[0] = pk2bf(x0.x * cc, x0.y * cc);
            avu[1] = pk2bf(x0.z * cc, x0.w * cc);
            avu[2] = pk2bf(x1.x * cc, x1.y * cc);
            avu[3] = pk2bf(x1.z * cc, x1.w * cc);
            acc[mt][0] = __builtin_amdgcn_mfma_f32_16x16x32_bf16(av, bv0, acc[mt][0], 0, 0, 0);
            acc[mt][1] = __builtin_amdgcn_mfma_f32_16x16x32_bf16(av, bv1, acc[mt][1], 0, 0, 0);
        }
    }

    // Fully-coalesced partial store: thread t owns 16 consecutive floats,
    // q = mt*8 + nt*4 + r (r contiguous inside each f32x4).
    float* pbase = partial + ((size_t)kc * NJ + j) * (128 * 16) + t * 16;
#pragma unroll
    for (int mt = 0; mt < 2; ++mt)
#pragma unroll
        for (int nt = 0; nt < 2; ++nt)
            *reinterpret_cast<f32x4*>(pbase + mt * 8 + nt * 4) = acc[mt][nt];
}

// ---------------------------------------------------------------------------
// reduce_k: s[b,j,e] = sum_kc partial[kc][j][t*16+q], inverting the wsum
// lane mapping. 65536 threads; loads coalesced across threads per kc.
// ---------------------------------------------------------------------------
__global__ __launch_bounds__(256) void reduce_k(
    const float* __restrict__ partial,   // [NKC][NJ][2048]
    float* __restrict__ s)               // [NB][NJ][NE]
{
    const int g   = blockIdx.x * 256 + threadIdx.x;   // 0..65535
    const int j   = g >> 11;
    const int rem = g & 2047;
    const int t   = rem >> 4;
    const int q   = rem & 15;
    const int wv  = t >> 6;
    const int ln  = t & 63;
    const int m   = ln & 15;
    const int quad = ln >> 4;
    const int mt  = q >> 3;
    const int nt  = (q >> 2) & 1;
    const int r   = q & 3;
    const int b   = (wv * 2 + mt) * 16 + quad * 4 + r;
    const int e   = nt * 16 + m;

    float sum = 0.f;
#pragma unroll 8
    for (int kc = 0; kc < NKC; ++kc)
        sum += partial[(size_t)kc * (NJ * 2048) + g];

    s[((size_t)b * NJ + j) * NE + e] = sum;
}

// ---------------------------------------------------------------------------
// squash_k: squash(s) -> out or Oacc accumulation. s is fully rewritten by
// reduce_k each round, so no re-zeroing needed.
// ---------------------------------------------------------------------------
__global__ void squash_k(const float* __restrict__ s, float* __restrict__ Oacc,
                         float* __restrict__ out, int final_round)
{
    const int b = blockIdx.x;
    const int t = threadIdx.x;
    const int j = t >> 3;
    const int eq = t & 7;
    const size_t off = ((size_t)b * NJ + j) * NE + 4 * eq;

    float4 v = *reinterpret_cast<const float4*>(s + off);

    float p = v.x * v.x + v.y * v.y + v.z * v.z + v.w * v.w;
    p += __shfl_xor(p, 1, 8);
    p += __shfl_xor(p, 2, 8);
    p += __shfl_xor(p, 4, 8);

    const float scale = p / ((1.0f + p) * sqrtf(p + 1e-7f));
    float4 o = make_float4(scale * v.x, scale * v.y, scale * v.z, scale * v.w);

    if (final_round) {
        *reinterpret_cast<float4*>(out + off) = o;
    } else {
        float4* op = reinterpret_cast<float4*>(Oacc + off);
        float4 ov = *op;
        *op = make_float4(ov.x + o.x, ov.y + o.y, ov.z + o.z, ov.w + o.w);
    }
}

extern "C" void kernel_launch(void* const* d_in, const int* in_sizes, int n_in,
                              void* d_out, int out_size, void* d_ws, size_t ws_size,
                              hipStream_t stream)
{
    (void)in_sizes; (void)n_in; (void)out_size; (void)ws_size;
    const float* x = (const float*)d_in[0];   // [64][2048][16]
    const float* W = (const float*)d_in[1];   // [32][2048][32][16]
    float* out = (float*)d_out;               // [64][32][32]

    // ws layout (≈100.5 MB of 512 MB):
    float* s    = (float*)d_ws;                       // 64K floats   (256 KB)
    float* Oacc = s + NB * NJ * NE;                   // 64K floats   (256 KB)
    float* lgt  = Oacc + NB * NJ * NE;                // [NJ][NI][NB] (16 MB)
    float* part = lgt + (size_t)NB * NJ * NI;         // [64][32][2048] (16 MB)
    short* xb   = (short*)(part + (size_t)NKC * NJ * 2048);    // 2M bf16 (4 MB)
    short* Wb   = xb + (size_t)NB * NI * ND;                   // 32M bf16 (64 MB)

    // zero Oacc only (s is fully written by reduce_k each round)
    hipMemsetAsync(Oacc, 0, (size_t)NB * NJ * NE * sizeof(float), stream);

    // pre-convert W and x to bf16 (fragment layouts)
    convw_k<<<(NJ * NIP * NE * 2) / 256, 256, 0, stream>>>(W, Wb);
    convx_k<<<(NB * NI * ND / 8) / 256, 256, 0, stream>>>(x, xb);

    dim3 gG(NJ, NI / 32);   // 32 x 64 blocks

    // round 0: uniform c = 1/32
    wsum_k<true><<<gG, 128, 0, stream>>>(x, Wb, lgt, part);
    reduce_k<<<65536 / 256, 256, 0, stream>>>(part, s);
    squash_k<<<NB, 256, 0, stream>>>(s, Oacc, out, 0);

    // round 1
    logits_k<<<gG, 256, 0, stream>>>(xb, Wb, Oacc, lgt);
    softmax_k<<<NB * NI / 256, 256, 0, stream>>>(lgt);
    wsum_k<false><<<gG, 128, 0, stream>>>(x, Wb, lgt, part);
    reduce_k<<<65536 / 256, 256, 0, stream>>>(part, s);
    squash_k<<<NB, 256, 0, stream>>>(s, Oacc, out, 0);

    // round 2
    logits_k<<<gG, 256, 0, stream>>>(xb, Wb, Oacc, lgt);
    softmax_k<<<NB * NI / 256, 256, 0, stream>>>(lgt);
    wsum_k<false><<<gG, 128, 0, stream>>>(x, Wb, lgt, part);
    reduce_k<<<65536 / 256, 256, 0, stream>>>(part, s);
    squash_k<<<NB, 256, 0, stream>>>(s, Oacc, out, 1);
}